// Round 7
// baseline (4115.347 us; speedup 1.0000x reference)
//
#include <hip/hip_runtime.h>

#define HIDN 150
#define NG   600     // 4*HIDN gates
#define NGP  640     // padded gate width / G row stride / scan slot count
#define TT   512
#define NBATCH 256
#define KPA  160     // padded K for H->next-layer A buffers
#define KPE  320     // padded K for embedding

typedef __attribute__((ext_vector_type(8))) short bf16x8;
typedef __attribute__((ext_vector_type(4))) float f32x4;

__device__ __forceinline__ unsigned short f2bf(float v) {
    unsigned int u = __builtin_bit_cast(unsigned int, v);
    u += 0x7fffu + ((u >> 16) & 1u);          // RNE
    return (unsigned short)(u >> 16);
}
__device__ __forceinline__ float bf2f(unsigned short h) {
    unsigned int u = ((unsigned int)h) << 16;
    return __builtin_bit_cast(float, u);
}

#define GLDS(gp, lp) __builtin_amdgcn_global_load_lds( \
    (const __attribute__((address_space(1))) unsigned int*)(gp), \
    (__attribute__((address_space(3))) unsigned int*)(lp), 16, 0, 0)

// scan slot for gate column n (n<600): u=n%150, g=n/150 -> s = (u>>4)*64 + g*16 + (u&15)
__device__ __forceinline__ int slot_of(int n) {
    int g = n / HIDN, u = n - g * HIDN;
    return ((u >> 4) << 6) + (g << 4) + (u & 15);
}

// ---------------- embedding split: emb[50000][300] fp32 -> embh/embl [50000][320] bf16 ----------------
__global__ __launch_bounds__(256) void embprep_kernel(
    const float* __restrict__ emb,
    unsigned short* __restrict__ eh, unsigned short* __restrict__ el)
{
    int i = blockIdx.x * 256 + threadIdx.x;
    if (i >= 50000 * KPE) return;
    int v = i / KPE, k = i - v * KPE;
    float x = (k < 300) ? emb[(size_t)v * 300 + k] : 0.f;
    unsigned short hi = f2bf(x);
    eh[i] = hi;
    el[i] = f2bf(x - bf2f(hi));
}

// ---------------- per-layer weight prep ----------------
// Wts now [160][640] fp32 Whh^T permuted, rows 150..159 zero (k padded for 4x40 quarters).
__global__ __launch_bounds__(256) void prep_kernel(
    const float* __restrict__ Wih, const float* __restrict__ Whh,
    const float* __restrict__ bih, const float* __restrict__ bhh,
    int K, int Kp,
    unsigned short* __restrict__ Wgh, unsigned short* __restrict__ Wgl,
    float* __restrict__ Wts, float* __restrict__ bsum)
{
    int i = blockIdx.x * 256 + threadIdx.x;
    int nW = NGP * Kp;
    if (i < nW) {
        int n = i / Kp, k = i - n * Kp;
        float w = (n < NG && k < K) ? Wih[(size_t)n * K + k] : 0.f;
        unsigned short hi = f2bf(w);
        Wgh[i] = hi;
        Wgl[i] = f2bf(w - bf2f(hi));
    } else if (i < nW + 160 * NGP) {
        int j = i - nW;
        int k = j / NGP, s = j - k * NGP;
        // invert slot: s -> u = (s>>6)*16 + (s&15), g = (s>>4)&3
        int u = ((s >> 6) << 4) + (s & 15);
        int g = (s >> 4) & 3;
        Wts[j] = (u < HIDN && k < HIDN) ? Whh[(size_t)(g * HIDN + u) * HIDN + k] : 0.f;
    } else if (i < nW + 160 * NGP + NGP) {
        int g = i - nW - 160 * NGP;
        bsum[g] = (g < NG) ? (bih[g] + bhh[g]) : 0.f;
    }
}

// ---------------- x_proj GEMM: split-bf16 MFMA ----------------
__global__ __launch_bounds__(256, 2) void gemm_kernel(
    const unsigned short* __restrict__ Ah, const unsigned short* __restrict__ Al,
    const int* __restrict__ gather,
    const unsigned short* __restrict__ Eh, const unsigned short* __restrict__ El,
    int Kp,
    const unsigned short* __restrict__ Wh, const unsigned short* __restrict__ Wl,
    const float* __restrict__ bsum, const int* __restrict__ lengths,
    float* __restrict__ G,                                       // [NBc*Tc][640] permuted
    int b_off, int t0, int lTc)
{
    int m0 = blockIdx.x * 128;
    int n0 = blockIdx.y * 128;
    int Tcm1 = (1 << lTc) - 1;
    if (lTc >= 7) {
        int b = b_off + (m0 >> lTc);
        if (t0 + (m0 & Tcm1) >= lengths[b]) return;
    }

    __shared__ __align__(16) unsigned short Ash[128][32];
    __shared__ __align__(16) unsigned short Asl[128][32];
    __shared__ __align__(16) unsigned short Bsh[128][32];
    __shared__ __align__(16) unsigned short Bsl[128][32];

    int tid = threadIdx.x, lane = tid & 63, wave = tid >> 6;

    const unsigned short* AhB = gather ? Eh : Ah;
    const unsigned short* AlB = gather ? El : Al;
    size_t ra[2], rb[2];
    int mrow[2];
    #pragma unroll
    for (int c2 = 0; c2 < 2; ++c2) {
        int mb = wave * 32 + c2 * 16;
        mrow[c2] = mb;
        int rg = m0 + mb + (lane >> 2);
        int bb = rg >> lTc, tl = rg & Tcm1;
        ra[c2] = gather ? (size_t)gather[(b_off + bb) * TT + t0 + tl] * (size_t)Kp
                        : ((size_t)bb * TT + t0 + tl) * (size_t)Kp;
        int nr = n0 + mb + (lane >> 2);
        rb[c2] = (size_t)nr * (size_t)Kp;
    }
    int klane = (lane & 3) * 8;

    f32x4 acc[4][4];
    #pragma unroll
    for (int i = 0; i < 4; ++i)
        #pragma unroll
        for (int j = 0; j < 4; ++j) acc[i][j] = (f32x4){0.f, 0.f, 0.f, 0.f};

    int fr = (lane >> 4) * 8;
    int ml = lane & 15;
    int mbase = (wave & 1) * 64;
    int nbase = (wave >> 1) * 64;

    for (int k0 = 0; k0 < Kp; k0 += 32) {
        #pragma unroll
        for (int c2 = 0; c2 < 2; ++c2) {
            GLDS(AhB + ra[c2] + k0 + klane, &Ash[mrow[c2]][0]);
            GLDS(AlB + ra[c2] + k0 + klane, &Asl[mrow[c2]][0]);
            GLDS(Wh  + rb[c2] + k0 + klane, &Bsh[mrow[c2]][0]);
            GLDS(Wl  + rb[c2] + k0 + klane, &Bsl[mrow[c2]][0]);
        }
        __syncthreads();

        bf16x8 afh[4], afl[4], bfh[4], bfl[4];
        #pragma unroll
        for (int i = 0; i < 4; ++i) {
            afh[i] = *(const bf16x8*)&Ash[mbase + i * 16 + ml][fr];
            afl[i] = *(const bf16x8*)&Asl[mbase + i * 16 + ml][fr];
            bfh[i] = *(const bf16x8*)&Bsh[nbase + i * 16 + ml][fr];
            bfl[i] = *(const bf16x8*)&Bsl[nbase + i * 16 + ml][fr];
        }
        #pragma unroll
        for (int i = 0; i < 4; ++i)
            #pragma unroll
            for (int j = 0; j < 4; ++j)
                acc[i][j] = __builtin_amdgcn_mfma_f32_16x16x32_bf16(afh[i], bfh[j], acc[i][j], 0, 0, 0);
        #pragma unroll
        for (int i = 0; i < 4; ++i)
            #pragma unroll
            for (int j = 0; j < 4; ++j)
                acc[i][j] = __builtin_amdgcn_mfma_f32_16x16x32_bf16(afh[i], bfl[j], acc[i][j], 0, 0, 0);
        #pragma unroll
        for (int i = 0; i < 4; ++i)
            #pragma unroll
            for (int j = 0; j < 4; ++j)
                acc[i][j] = __builtin_amdgcn_mfma_f32_16x16x32_bf16(afl[i], bfh[j], acc[i][j], 0, 0, 0);
        __syncthreads();
    }

    // epilogue: C/D layout col=lane&15, row=(lane>>4)*4+r; store into permuted slot
    int rq = lane >> 4;
    #pragma unroll
    for (int i = 0; i < 4; ++i) {
        int mg = m0 + mbase + i * 16 + rq * 4;
        #pragma unroll
        for (int j = 0; j < 4; ++j) {
            int ng = n0 + nbase + j * 16 + ml;
            if (ng < NG) {
                float bz = bsum[ng];
                int s = slot_of(ng);
                #pragma unroll
                for (int r = 0; r < 4; ++r)
                    G[(size_t)(mg + r) * NGP + s] = acc[i][j][r] + bz;
            }
        }
    }
}

// ---------------- recurrent scan v9: 4-way k-split (attack the LDS pipe) ----------------
// DIAGNOSIS REVISION (r1-r6): scan is LDS-PIPE-bound, not register-spill-bound. Old design:
// every thread read ALL 150 h from LDS each step (38 ds_read_b128) + ~10 weight-tail reads
// = 48 LDS instrs/thread/step; 480/CU-step x ~6-12cyc = the measured ~3400 cyc/step. Weight
// overflow spills to AGPR (unified RF, ~free) - hence VGPR=84 never mattered.
// v9: k padded to 160, split in 4 quarters of 40. Lane l (q=l>>4, u_loc=l&15) computes
// partials for ALL 4 gates of its u over k-quarter q only: h-reads 38->10 b128. Weights:
// 32 kk-quads (128 scalars) in named registers, 8 kk-quads in LDS (8 reads). Quarter
// partials combined via shfl_xor(16)+shfl_xor(32) butterfly (VALU pipe, free). After
// reduce each lane holds its own gate's full sum -> activation/gate-gather/owner code
// UNCHANGED. G bias added pre-reduce on the owning lane. LDS instrs/step: 48 -> 19.
#define KQ   40          // k per quarter (K padded to 160)
#define LKK  8           // kk 32..39 quads live in LDS

#define QR(X) X(0) X(1) X(2) X(3) X(4) X(5) X(6) X(7) X(8) X(9) \
              X(10) X(11) X(12) X(13) X(14) X(15) X(16) X(17) X(18) X(19) \
              X(20) X(21) X(22) X(23) X(24) X(25) X(26) X(27) X(28) X(29) \
              X(30) X(31)

#define DECLW(kk) float wA##kk = Wq[(kk)*NGP +  0], wB##kk = Wq[(kk)*NGP + 16], \
                        wC##kk = Wq[(kk)*NGP + 32], wD##kk = Wq[(kk)*NGP + 48];
#define PINW(kk)  asm volatile("" : "+v"(wA##kk), "+v"(wB##kk), "+v"(wC##kk), "+v"(wD##kk));
// one j covers kk = 4j..4j+3 <-> h4.x..w ; 16 FMAs, 4 independent chains p0..p3
#define FMAJ(j,k0,k1,k2,k3) { float4 h4 = *(const float4*)&hp[KQ*q + 4*(j)]; \
  p0 += wA##k0*h4.x; p1 += wB##k0*h4.x; p2 += wC##k0*h4.x; p3 += wD##k0*h4.x; \
  p0 += wA##k1*h4.y; p1 += wB##k1*h4.y; p2 += wC##k1*h4.y; p3 += wD##k1*h4.y; \
  p0 += wA##k2*h4.z; p1 += wB##k2*h4.z; p2 += wC##k2*h4.z; p3 += wD##k2*h4.z; \
  p0 += wA##k3*h4.w; p1 += wB##k3*h4.w; p2 += wC##k3*h4.w; p3 += wD##k3*h4.w; }
// LDS-resident kk quads (m = kk-32): wl[m][tid] = {gate0..3 weights for that kk}
#define FMAL(j,m0,m1,m2,m3) { float4 h4 = *(const float4*)&hp[KQ*q + 4*(j)]; \
  float4 q0 = *(const float4*)&wl[m0][tid][0]; \
  float4 q1 = *(const float4*)&wl[m1][tid][0]; \
  float4 q2 = *(const float4*)&wl[m2][tid][0]; \
  float4 q3 = *(const float4*)&wl[m3][tid][0]; \
  p0 += q0.x*h4.x; p1 += q0.y*h4.x; p2 += q0.z*h4.x; p3 += q0.w*h4.x; \
  p0 += q1.x*h4.y; p1 += q1.y*h4.y; p2 += q1.z*h4.y; p3 += q1.w*h4.y; \
  p0 += q2.x*h4.z; p1 += q2.y*h4.z; p2 += q2.z*h4.z; p3 += q2.w*h4.z; \
  p0 += q3.x*h4.w; p1 += q3.y*h4.w; p2 += q3.z*h4.w; p3 += q3.w*h4.w; }

__global__ __launch_bounds__(640, 2)
void scan_kernel(
    const float* __restrict__ G,       // [NBc][Tc][640] permuted x_proj+bias
    const float* __restrict__ Wt,      // [160][640] permuted Whh^T (rows 150..159 zero)
    const int*   __restrict__ lengths,
    unsigned short* __restrict__ Aout, // [NBc][512][160] bf16-hi h, or null (layer 3)
    unsigned short* __restrict__ Alout,
    float* __restrict__ hnb,           // [256][150]
    float* __restrict__ hst, float* __restrict__ cst,   // [NBc][150] carries
    int b_off, int t0, int Tc)
{
    __shared__ __align__(16) float h_s[2][160];
    __shared__ __align__(16) float wl[LKK][NGP][4];   // 80 KiB: kk=32..39 weight quads

    int tid = threadIdx.x;
    int lane = tid & 63, w = tid >> 6;
    int u_loc = lane & 15, q = (lane >> 4) & 3;       // q = k-quarter AND own gate index
    int u = w * 16 + u_loc;
    bool own = (lane < 16) && (u < HIDN);

    int l0 = blockIdx.x;
    int b  = b_off + l0;
    int len = lengths[b];
    int tmax = min(len, t0 + Tc);

    // per-lane weight base: rows KQ*q.., columns w*64 + u_loc + g'*16  (g' offset 0/16/32/48)
    const float* Wq = Wt + (size_t)(KQ * q) * NGP + (tid - q * 16);

    // ---- 128 weight scalars (kk 0..31 x 4 gates), SSA + pinned ----
    QR(DECLW)
    QR(PINW)

    // ---- kk 32..39 quads into LDS: wl[m][tid][g'] ----
    #pragma unroll
    for (int m = 0; m < LKK; ++m) {
        wl[m][tid][0] = Wq[(32 + m) * NGP +  0];
        wl[m][tid][1] = Wq[(32 + m) * NGP + 16];
        wl[m][tid][2] = Wq[(32 + m) * NGP + 32];
        wl[m][tid][3] = Wq[(32 + m) * NGP + 48];
    }

    float c = 0.f;
    if (tid < 160) { h_s[0][tid] = 0.f; h_s[1][tid] = 0.f; }
    if (tid < HIDN && t0 > 0) h_s[0][tid] = hst[l0 * HIDN + tid];
    if (own && t0 > 0) c = cst[l0 * HIDN + u];

    bool isg = (q == 2);                      // own gate 2 -> tanh
    const float* Gbase = G + (size_t)l0 * Tc * NGP + tid;
    __syncthreads();

    int p = 0;
    float gnext = (t0 < tmax) ? Gbase[(size_t)0] : 0.f;
    for (int t = t0; t < tmax; ++t) {
        float gcur = gnext;
        if (t + 1 < tmax) gnext = Gbase[(size_t)(t + 1 - t0) * NGP];   // prefetch next step
        const float* hp = &h_s[p][0];
        float p0 = 0.f, p1 = 0.f, p2 = 0.f, p3 = 0.f;   // per-gate partials over k-quarter q
        FMAJ(0,0,1,2,3)    FMAJ(1,4,5,6,7)    FMAJ(2,8,9,10,11)   FMAJ(3,12,13,14,15)
        FMAJ(4,16,17,18,19) FMAJ(5,20,21,22,23) FMAJ(6,24,25,26,27) FMAJ(7,28,29,30,31)
        FMAL(8,0,1,2,3)    FMAL(9,4,5,6,7)
        // add own G (x_proj+bias for column (gate=q, u)) into gate q's partial, pre-reduce
        if      (q == 0) p0 += gcur;
        else if (q == 1) p1 += gcur;
        else if (q == 2) p2 += gcur;
        else             p3 += gcur;
        // butterfly across the 4 k-quarters (lanes u_loc, +16, +32, +48)
        p0 += __shfl_xor(p0, 16, 64); p1 += __shfl_xor(p1, 16, 64);
        p2 += __shfl_xor(p2, 16, 64); p3 += __shfl_xor(p3, 16, 64);
        p0 += __shfl_xor(p0, 32, 64); p1 += __shfl_xor(p1, 32, 64);
        p2 += __shfl_xor(p2, 32, 64); p3 += __shfl_xor(p3, 32, 64);
        // own gate's full pre-activation
        float a = (q == 0) ? p0 : (q == 1) ? p1 : (q == 2) ? p2 : p3;
        // per-lane activation: sigmoid (i,f,o) or tanh (g) = 2*sigmoid(2a)-1
        float bb = isg ? 2.f * a : a;
        float e  = __expf(-bb);
        float r  = 1.f / (1.f + e);
        float av = isg ? 2.f * r - 1.f : r;
        // wave-local gate gather (unchanged: lane u_loc+16g' holds gate g')
        float fv = __shfl(av, u_loc + 16, 64);
        float gv = __shfl(av, u_loc + 32, 64);
        float ov = __shfl(av, u_loc + 48, 64);
        if (own) {
            float cn = fv * c + av * gv;       // av = i-gate on owner lanes (q==0)
            float e2 = __expf(-2.f * cn);
            float th = 2.f / (1.f + e2) - 1.f;
            float hv = ov * th;
            c = cn;
            h_s[p ^ 1][u] = hv;
            if (Aout) {
                size_t off = ((size_t)l0 * TT + t) * KPA + u;
                unsigned short hi = f2bf(hv);
                Aout[off]  = hi;
                Alout[off] = f2bf(hv - bf2f(hi));
            }
            if (t == len - 1) hnb[b * HIDN + u] = hv;
        }
        __syncthreads();
        p ^= 1;
    }

    if (own) {
        hst[l0 * HIDN + u] = h_s[p][u];
        cst[l0 * HIDN + u] = c;
    }
}

// ---------------- fc1+relu+fc2 head ----------------
__global__ __launch_bounds__(256) void head_kernel(
    const float* __restrict__ hnb, const float* __restrict__ fc1_w,
    const float* __restrict__ fc1_b, const float* __restrict__ fc2_w,
    const float* __restrict__ fc2_b, float* __restrict__ out)
{
    __shared__ float hs[HIDN];
    __shared__ float zs[HIDN];
    int b = blockIdx.x, tid = threadIdx.x;
    if (tid < HIDN) hs[tid] = hnb[b * HIDN + tid];
    __syncthreads();
    if (tid < HIDN) {
        float acc = fc1_b[tid];
        const float* wr = fc1_w + (size_t)tid * HIDN;
        #pragma unroll 5
        for (int k = 0; k < HIDN; ++k) acc += wr[k] * hs[k];
        zs[tid] = fmaxf(acc, 0.f);
    }
    __syncthreads();
    if (tid == 0) {
        float s = fc2_b[0];
        for (int k = 0; k < HIDN; ++k) s += fc2_w[k] * zs[k];
        out[b] = s;
    }
}

extern "C" void kernel_launch(void* const* d_in, const int* in_sizes, int n_in,
                              void* d_out, int out_size, void* d_ws, size_t ws_size,
                              hipStream_t stream)
{
    const int*   x       = (const int*)d_in[0];
    const int*   lengths = (const int*)d_in[1];
    const float* emb     = (const float*)d_in[2];
    const float *Wih[4], *Whh[4], *bih[4], *bhh[4];
    for (int l = 0; l < 4; ++l) {
        Wih[l] = (const float*)d_in[3 + 4 * l];
        Whh[l] = (const float*)d_in[4 + 4 * l];
        bih[l] = (const float*)d_in[5 + 4 * l];
        bhh[l] = (const float*)d_in[6 + 4 * l];
    }
    const float* fc1_w = (const float*)d_in[19];
    const float* fc1_b = (const float*)d_in[20];
    const float* fc2_w = (const float*)d_in[21];
    const float* fc2_b = (const float*)d_in[22];

    int Kl[4]  = {300, 150, 150, 150};
    int Kp[4]  = {KPE, KPA, KPA, KPA};
    size_t wgoff[4];
    size_t wgacc = 0;
    for (int l = 0; l < 4; ++l) { wgoff[l] = wgacc; wgacc += 2 * (size_t)NGP * Kp[l]; }

    // ---- adaptive workspace sizing ----
    size_t wf = ws_size / sizeof(float);
    const size_t WFIX = 409600 + 2560 + 38400 + 512000 + 16000000;   // Wts now 4*160*640
    int NBc = 0, Tc = 0;
    for (int nb = 256; nb >= 16; nb >>= 1) {
        for (int tc = 512; tc >= 8; tc >>= 1) {
            size_t need = WFIX + (size_t)nb * 300
                        + (size_t)nb * TT * KPA                   // Ah+Al (2 bufs of bf16)
                        + (size_t)nb * tc * NGP;                  // G chunk (stride 640)
            if (need <= wf) { NBc = nb; Tc = tc; break; }
        }
        if (NBc) break;
    }
    if (!NBc) return;
    int lTc = __builtin_ctz(Tc);

    float* ws  = (float*)d_ws;
    float* Wts = ws;                                    // 4 * 102400 (permuted, 160 rows)
    float* bsm = Wts + 409600;                          // 4 * 640
    float* hnb = bsm + 2560;                            // 256*150
    unsigned short* Wg = (unsigned short*)(hnb + 38400);        // 1,024,000 ushorts
    unsigned short* embh = Wg + 1024000;                        // 16,000,000 ushorts
    unsigned short* embl = embh + 16000000;                     // 16,000,000 ushorts
    float* hst = (float*)(embl + 16000000);             // NBc*150
    float* cst = hst + (size_t)NBc * HIDN;              // NBc*150
    unsigned short* Ahh = (unsigned short*)(cst + (size_t)NBc * HIDN);  // NBc*512*160
    unsigned short* Ahl = Ahh + (size_t)NBc * TT * KPA;                 // NBc*512*160
    float* G   = (float*)(Ahl + (size_t)NBc * TT * KPA);                // NBc*Tc*640

    embprep_kernel<<<(50000 * KPE + 255) / 256, 256, 0, stream>>>(emb, embh, embl);
    for (int l = 0; l < 4; ++l) {
        int total = NGP * Kp[l] + 160 * NGP + NGP;
        prep_kernel<<<(total + 255) / 256, 256, 0, stream>>>(
            Wih[l], Whh[l], bih[l], bhh[l], Kl[l], Kp[l],
            Wg + wgoff[l], Wg + wgoff[l] + (size_t)NGP * Kp[l],
            Wts + l * 102400, bsm + l * 640);
    }

    int nTc = TT / Tc;
    int nBc = NBATCH / NBc;
    dim3 ggrid((unsigned)(NBc * Tc / 128), 5);
    for (int bc = 0; bc < nBc; ++bc) {
        int b_off = bc * NBc;
        for (int l = 0; l < 4; ++l) {
            const unsigned short* Wh = Wg + wgoff[l];
            const unsigned short* Wl = Wh + (size_t)NGP * Kp[l];
            for (int tc = 0; tc < nTc; ++tc) {
                int t0 = tc * Tc;
                gemm_kernel<<<ggrid, 256, 0, stream>>>(
                    (l == 0) ? nullptr : Ahh, (l == 0) ? nullptr : Ahl,
                    (l == 0) ? x : nullptr, embh, embl,
                    Kp[l], Wh, Wl, bsm + l * 640, lengths, G, b_off, t0, lTc);
                scan_kernel<<<NBc, 640, 0, stream>>>(
                    G, Wts + l * 102400, lengths,
                    (l == 3) ? nullptr : Ahh, (l == 3) ? nullptr : Ahl,
                    hnb, hst, cst, b_off, t0, Tc);
            }
        }
    }
    head_kernel<<<256, 256, 0, stream>>>(hnb, fc1_w, fc1_b, fc2_w, fc2_b, (float*)d_out);
}